// Round 12
// baseline (382.207 us; speedup 1.0000x reference)
//
#include <hip/hip_runtime.h>
#include <math.h>

// Problem: B=2, N=64, D=16.
// C_{b,n,m,k} = diag(Q_n) T_k diag(K_m), 131072 16x16 matrices.
// det/trace closed-form; sigma via one-sided block-Jacobi (4 lanes x 4 cols,
// GF(4) spread schedule, mov_dpp comm, fast scaled rotations, packed fp32);
// rho via normalized repeated squaring + geometric tail (packed fp32).
// R12: k_setup shrunk to 9 blocks (QK + detT, the k_main producers);
// V compute moved into k_main as trailing blocks [4096,4864) (consumed only
// by k_out, overlaps svd/rho and backfills the drain); k_out sr loads as v2f.

#define EPSF 1e-6f
#define SWEEPS 5
#define RHO_J 8

// workspace float offsets
#define WS_Q    0         // [2][64][16]            = 2048
#define WS_K    2048      // [2][64][16]            = 2048
#define WS_DETT 4096      // [16]
#define WS_V    4352      // [2][64][6][16][16]     = 196608
#define WS_SIGN 200960    // [2][64][64][6][16]     = 786432

typedef float v2f __attribute__((ext_vector_type(2)));

// quad_perm DPP: ctrl = p0|p1<<2|p2<<4|p3<<6; XOR masks: 1->0xB1, 2->0x4E, 3->0x1B
template <int CTRL>
__device__ __forceinline__ float dppf(float v) {
  return __int_as_float(__builtin_amdgcn_mov_dpp(__float_as_int(v), CTRL, 0xF, 0xF, true));
}
template <int CTRL>
__device__ __forceinline__ v2f dpp2(v2f v) {
  v2f r;
  r.x = dppf<CTRL>(v.x);
  r.y = dppf<CTRL>(v.y);
  return r;
}
__device__ __forceinline__ v2f pkfma(v2f a, v2f b, v2f c) {
  return __builtin_elementwise_fma(a, b, c);
}
__device__ __forceinline__ v2f bc2(float s) { v2f r; r.x = s; r.y = s; return r; }
__device__ __forceinline__ float fsqrt_fast(float x) { return __builtin_amdgcn_sqrtf(x); }
__device__ __forceinline__ float frcp_fast(float x)  { return __builtin_amdgcn_rcpf(x); }
__device__ __forceinline__ float frsq_fast(float x)  { return __builtin_amdgcn_rsqf(x); }

// ---------------- small setup: QK (8 blocks) | detT (1 block) ----------------
__global__ __launch_bounds__(256) void k_setup(const float* __restrict__ X,
                                               const float* __restrict__ Wk,
                                               const float* __restrict__ Wq,
                                               const float* __restrict__ T,
                                               float* __restrict__ Q,
                                               float* __restrict__ Kout,
                                               float* __restrict__ detT) {
  int blk = blockIdx.x;
  if (blk < 8) {
    int t = blk * 256 + threadIdx.x;  // 2048 threads for Q,K
    int i = t & 15, bn = t >> 4;
    const float* x = X + bn * 16;
    float q = 0.f, kk = 0.f;
#pragma unroll
    for (int d = 0; d < 16; ++d) {
      float xv = x[d];
      q  += xv * Wq[d * 16 + i];
      kk += xv * Wk[d * 16 + i];
    }
    Q[t] = q; Kout[t] = kk;
  } else {
    // det(T_k) via LU with partial pivoting
    __shared__ float A[16][16][16];  // [k][i][j]
    for (int idx = threadIdx.x; idx < 4096; idx += 256) {
      int i = idx >> 8, j = (idx >> 4) & 15, kk = idx & 15;
      A[kk][i][j] = T[idx];          // T[i,j,k] at i*256+j*16+k
    }
    __syncthreads();
    int k = threadIdx.x;
    if (k < 16) {
      float det = 1.0f;
      for (int c = 0; c < 16; ++c) {
        int p = c; float mx = fabsf(A[k][c][c]);
        for (int r = c + 1; r < 16; ++r) {
          float v = fabsf(A[k][r][c]);
          if (v > mx) { mx = v; p = r; }
        }
        if (mx == 0.0f) { det = 0.0f; break; }
        if (p != c) {
          det = -det;
          for (int cc = c; cc < 16; ++cc) {
            float tmp = A[k][c][cc]; A[k][c][cc] = A[k][p][cc]; A[k][p][cc] = tmp;
          }
        }
        float piv = A[k][c][c];
        det *= piv;
        float inv = 1.0f / piv;
        for (int r = c + 1; r < 16; ++r) {
          float f = A[k][r][c] * inv;
          for (int cc = c + 1; cc < 16; ++cc) A[k][r][cc] -= f * A[k][c][cc];
        }
      }
      detT[k] = det;
    }
  }
}

// ---------------- fast scaled Jacobi helpers (packed) ----------------
// Actual column = d * stored column. a' = a - t*(db/da)*b, b' = b + t*(da/db)*a,
// da*=c, db*=c. Norms na,nb are TRUE squared norms (Rutishauser-carried).

__device__ __forceinline__ void rot2(v2f (&a)[8], v2f (&b)[8],
                                     float& na, float& nb,
                                     float& da, float& ida,
                                     float& db, float& idb) {
  v2f g0 = bc2(0.f), g1 = bc2(0.f);
#pragma unroll
  for (int i = 0; i < 4; ++i) {
    g0 = pkfma(a[i], b[i], g0);
    g1 = pkfma(a[i + 4], b[i + 4], g1);
  }
  v2f g = g0 + g1;
  float ga = (da * db) * (g.x + g.y);   // true gamma
  float w = nb - na;
  float v = ga + ga;
  float h = fsqrt_fast(fmaf(w, w, v * v));
  float t = v * frcp_fast(w + copysignf(h, w));
  t = (ga == 0.0f) ? 0.0f : t;
  float p = fmaf(t, t, 1.0f);
  float cc = frsq_fast(p);
  float icc = p * cc;                 // 1/cc
  float tg = t * ga;
  v2f t1 = bc2(-t * (db * ida));
  v2f t2 = bc2( t * (da * idb));
#pragma unroll
  for (int i = 0; i < 8; ++i) {
    v2f ai = a[i];
    a[i] = pkfma(t1, b[i], ai);
    b[i] = pkfma(t2, ai, b[i]);
  }
  na -= tg; nb += tg;
  da *= cc; db *= cc; ida *= icc; idb *= icc;
}

// cross-lane fast rotation: partner column at same slot in XOR-partner lane.
template <int CTRL>
__device__ __forceinline__ void xrot(v2f (&a)[8], float& na,
                                     float& d, float& id, bool top) {
  v2f oth[8];
#pragma unroll
  for (int i = 0; i < 8; ++i) oth[i] = dpp2<CTRL>(a[i]);
  float on = dppf<CTRL>(na);
  float od = dppf<CTRL>(d);
  float al = top ? na : on, be = top ? on : na;
  v2f g0 = bc2(0.f), g1 = bc2(0.f);
#pragma unroll
  for (int i = 0; i < 4; ++i) {
    g0 = pkfma(a[i], oth[i], g0);
    g1 = pkfma(a[i + 4], oth[i + 4], g1);
  }
  v2f g = g0 + g1;
  float ga = (d * od) * (g.x + g.y);
  float w = be - al;
  float v = ga + ga;
  float h = fsqrt_fast(fmaf(w, w, v * v));
  float t = v * frcp_fast(w + copysignf(h, w));
  t = (ga == 0.0f) ? 0.0f : t;
  float p = fmaf(t, t, 1.0f);
  float cc = frsq_fast(p);
  float icc = p * cc;
  float tg = t * ga;
  v2f coef = bc2((top ? -t : t) * (od * id));
#pragma unroll
  for (int i = 0; i < 8; ++i) a[i] = pkfma(coef, oth[i], a[i]);
  na += top ? -tg : tg;
  d *= cc; id *= icc;
}

// config-transition move of one slot's column+norm+scales (XOR within quad)
template <int CTRL>
__device__ __forceinline__ void tmov(v2f (&a)[8], float& na,
                                     float& d, float& id) {
#pragma unroll
  for (int i = 0; i < 8; ++i) a[i] = dpp2<CTRL>(a[i]);
  na = dppf<CTRL>(na);
  d = dppf<CTRL>(d);
  id = dppf<CTRL>(id);
}

// ---------------- SVD body: features det/trace/rank/smin/smax ----------------
__device__ __forceinline__ void svd_body(int blk, const float* __restrict__ Q,
                                         const float* __restrict__ K,
                                         const float* __restrict__ T,
                                         const float* __restrict__ detT,
                                         float* __restrict__ Sign) {
  int gtid = blk * 256 + threadIdx.x;
  int gid = gtid >> 2;          // matrix id, < 131072
  int l = threadIdx.x & 3;      // quad lane = group id
  int k = gid & 15, m = (gid >> 4) & 63, n = (gid >> 10) & 63, b = gid >> 16;
  const float* qrow = Q + (b * 64 + n) * 16;
  const float* krow = K + (b * 64 + m) * 16;

  float qv[16];
#pragma unroll
  for (int i = 0; i < 16; ++i) qv[i] = qrow[i];

  float trace = 0.f, pq = 1.f, pk = 1.f;
#pragma unroll
  for (int i = 0; i < 16; ++i) {
    float kv = krow[i];
    pq *= qv[i]; pk *= kv;
    trace += qv[i] * kv * T[i * 272 + k];   // T[i,i,k]
  }
  float det = pq * pk * detT[k];

  // init in slope-0 config: slot s holds col (x=s, y=l), col index 4s+l
  v2f c0[8], c1[8], c2[8], c3[8];
  float nn0, nn1, nn2, nn3;
  {
    int j0 = l, j1 = 4 + l, j2 = 8 + l, j3 = 12 + l;
    float k0 = krow[j0], k1 = krow[j1], k2 = krow[j2], k3 = krow[j3];
#pragma unroll
    for (int i = 0; i < 8; ++i) {
      float qa = qv[2 * i], qb = qv[2 * i + 1];
      int ra = (2 * i) * 256, rb = (2 * i + 1) * 256;
      c0[i].x = qa * T[ra + j0 * 16 + k] * k0; c0[i].y = qb * T[rb + j0 * 16 + k] * k0;
      c1[i].x = qa * T[ra + j1 * 16 + k] * k1; c1[i].y = qb * T[rb + j1 * 16 + k] * k1;
      c2[i].x = qa * T[ra + j2 * 16 + k] * k2; c2[i].y = qb * T[rb + j2 * 16 + k] * k2;
      c3[i].x = qa * T[ra + j3 * 16 + k] * k3; c3[i].y = qb * T[rb + j3 * 16 + k] * k3;
    }
    v2f a0 = bc2(0.f), a1 = bc2(0.f), a2 = bc2(0.f), a3 = bc2(0.f);
#pragma unroll
    for (int i = 0; i < 8; ++i) {
      a0 = pkfma(c0[i], c0[i], a0);
      a1 = pkfma(c1[i], c1[i], a1);
      a2 = pkfma(c2[i], c2[i], a2);
      a3 = pkfma(c3[i], c3[i], a3);
    }
    nn0 = a0.x + a0.y; nn1 = a1.x + a1.y; nn2 = a2.x + a2.y; nn3 = a3.x + a3.y;
  }
  float d0 = 1.f, d1 = 1.f, d2 = 1.f, d3 = 1.f;
  float i0 = 1.f, i1 = 1.f, i2 = 1.f, i3 = 1.f;

  bool r1 = (l & 1) == 0;   // top role for delta=1
  bool r2 = (l & 2) == 0;   // top role for delta=2 and delta=3

#define INTRA6() { rot2(c0,c1,nn0,nn1,d0,i0,d1,i1); rot2(c2,c3,nn2,nn3,d2,i2,d3,i3); \
                   rot2(c0,c2,nn0,nn2,d0,i0,d2,i2); rot2(c1,c3,nn1,nn3,d1,i1,d3,i3); \
                   rot2(c0,c3,nn0,nn3,d0,i0,d3,i3); rot2(c1,c2,nn1,nn2,d1,i1,d2,i2); }

  for (int sw = 0; sw < SWEEPS; ++sw) {
    // cross-lane phases (same-x pairs), done in slope-0 layout
    xrot<0xB1>(c0, nn0, d0, i0, r1); xrot<0xB1>(c1, nn1, d1, i1, r1);
    xrot<0xB1>(c2, nn2, d2, i2, r1); xrot<0xB1>(c3, nn3, d3, i3, r1);
    xrot<0x4E>(c0, nn0, d0, i0, r2); xrot<0x4E>(c1, nn1, d1, i1, r2);
    xrot<0x4E>(c2, nn2, d2, i2, r2); xrot<0x4E>(c3, nn3, d3, i3, r2);
    xrot<0x1B>(c0, nn0, d0, i0, r2); xrot<0x1B>(c1, nn1, d1, i1, r2);
    xrot<0x1B>(c2, nn2, d2, i2, r2); xrot<0x1B>(c3, nn3, d3, i3, r2);

    INTRA6();                                   // slope 0
    tmov<0xB1>(c1, nn1, d1, i1); tmov<0x4E>(c2, nn2, d2, i2); tmov<0x1B>(c3, nn3, d3, i3);
    INTRA6();                                   // slope 1
    tmov<0x1B>(c1, nn1, d1, i1); tmov<0xB1>(c2, nn2, d2, i2); tmov<0x4E>(c3, nn3, d3, i3);
    INTRA6();                                   // slope 2
    tmov<0xB1>(c1, nn1, d1, i1); tmov<0x4E>(c2, nn2, d2, i2); tmov<0x1B>(c3, nn3, d3, i3);
    INTRA6();                                   // slope 3
    tmov<0x1B>(c1, nn1, d1, i1); tmov<0xB1>(c2, nn2, d2, i2); tmov<0x4E>(c3, nn3, d3, i3);

    if (sw < SWEEPS - 1) {
      // per-sweep rescale: fold scales into columns (bounds dynamic range)
      v2f s0 = bc2(d0), s1 = bc2(d1), s2 = bc2(d2), s3 = bc2(d3);
#pragma unroll
      for (int i = 0; i < 8; ++i) {
        c0[i] *= s0; c1[i] *= s1; c2[i] *= s2; c3[i] *= s3;
      }
      d0 = d1 = d2 = d3 = 1.f;
      i0 = i1 = i2 = i3 = 1.f;
    }
  }
#undef INTRA6

  // final norms: true sigma = d * ||stored col|| (last-sweep scales folded here)
  v2f a0 = bc2(0.f), a1 = bc2(0.f), a2 = bc2(0.f), a3 = bc2(0.f);
#pragma unroll
  for (int i = 0; i < 8; ++i) {
    a0 = pkfma(c0[i], c0[i], a0);
    a1 = pkfma(c1[i], c1[i], a1);
    a2 = pkfma(c2[i], c2[i], a2);
    a3 = pkfma(c3[i], c3[i], a3);
  }
  float s0 = d0 * fsqrt_fast(a0.x + a0.y), s1 = d1 * fsqrt_fast(a1.x + a1.y);
  float s2 = d2 * fsqrt_fast(a2.x + a2.y), s3 = d3 * fsqrt_fast(a3.x + a3.y);
  float lmin = fminf(fminf(s0, s1), fminf(s2, s3));
  float lmax = fmaxf(fmaxf(s0, s1), fmaxf(s2, s3));
  float lsum = __logf(s0 + EPSF) + __logf(s1 + EPSF) +
               __logf(s2 + EPSF) + __logf(s3 + EPSF);
  lmin = fminf(lmin, dppf<0xB1>(lmin));
  lmax = fmaxf(lmax, dppf<0xB1>(lmax));
  lsum += dppf<0xB1>(lsum);
  lmin = fminf(lmin, dppf<0x4E>(lmin));
  lmax = fmaxf(lmax, dppf<0x4E>(lmax));
  lsum += dppf<0x4E>(lsum);
  if (l == 0) {
    float* sp = Sign + (((b * 64 + n) * 64 + m) * 6) * 16 + k;
    sp[0]  = det;
    sp[16] = trace;
    sp[32] = lsum;
    sp[48] = lmin;
    sp[64] = lmax;
  }
}

// ---------------- rho quarter-product (packed, quad_perm broadcast) ----------------
template <int SRCL>
__device__ __forceinline__ void rho_quarter(v2f (&a)[4][8], v2f (&acc)[4][8]) {
  constexpr int CTRL = SRCL | (SRCL << 2) | (SRCL << 4) | (SRCL << 6);  // quad bcast
#pragma unroll
  for (int c = 0; c < 4; ++c) {        // global column kk = SRCL*4 + c
    v2f colk[8];
#pragma unroll
    for (int i = 0; i < 8; ++i) colk[i] = dpp2<CTRL>(a[c][i]);  // A[.][kk]
    constexpr int R = SRCL * 4;        // row base (c added below, both static)
#pragma unroll
    for (int jj = 0; jj < 4; ++jj) {
      int r = R + c;                   // static after unroll
      float f = (r & 1) ? a[jj][r >> 1].y : a[jj][r >> 1].x;  // A[kk][own col jj]
      v2f fv = bc2(f);
      if (SRCL == 0 && c == 0) {
#pragma unroll
        for (int i = 0; i < 8; ++i) acc[jj][i] = colk[i] * fv;   // first write: no init
      } else {
#pragma unroll
        for (int i = 0; i < 8; ++i) acc[jj][i] = pkfma(colk[i], fv, acc[jj][i]);
      }
    }
  }
}

// ---------------- rho body: feature 5 (spectral radius) ----------------
__device__ __forceinline__ void rho_body(int blk, const float* __restrict__ Q,
                                         const float* __restrict__ K,
                                         const float* __restrict__ T,
                                         float* __restrict__ Sign) {
  int gtid = blk * 256 + threadIdx.x;
  int gid = gtid >> 2;              // matrix id, < 131072
  int l = threadIdx.x & 3;
  int k = gid & 15, m = (gid >> 4) & 63, n = (gid >> 10) & 63, b = gid >> 16;
  const float* qrow = Q + (b * 64 + n) * 16;
  const float* krow = K + (b * 64 + m) * 16;

  v2f a[4][8];
#pragma unroll
  for (int jj = 0; jj < 4; ++jj) {
    int j = 4 * l + jj;
    float w = qrow[j] * krow[j];
#pragma unroll
    for (int i = 0; i < 8; ++i) {
      a[jj][i].x = T[(2 * i) * 256 + j * 16 + k] * w;
      a[jj][i].y = T[(2 * i + 1) * 256 + j * 16 + k] * w;
    }
  }

  // L = sum_{i<J} log(ss_i)*2^-(i+1) + log(ss_J)*2^-J (geometric tail)
  float L = 0.0f, wgt = 0.5f;
  for (int it = 0; it <= RHO_J; ++it) {
    v2f p0 = bc2(0.f), p1 = bc2(0.f), p2 = bc2(0.f), p3 = bc2(0.f);
#pragma unroll
    for (int i = 0; i < 8; ++i) {
      p0 = pkfma(a[0][i], a[0][i], p0);
      p1 = pkfma(a[1][i], a[1][i], p1);
      p2 = pkfma(a[2][i], a[2][i], p2);
      p3 = pkfma(a[3][i], a[3][i], p3);
    }
    v2f ps = (p0 + p1) + (p2 + p3);
    float ss = ps.x + ps.y;
    ss += dppf<0xB1>(ss);
    ss += dppf<0x4E>(ss);
    float w2 = (it == RHO_J) ? (wgt + wgt) : wgt;
    L = fmaf(__logf(ss), w2, L);
    wgt *= 0.5f;
    if (it == RHO_J) break;
    float s = (ss > 0.0f) ? frcp_fast(ss) : 0.0f;

    v2f acc[4][8];
    rho_quarter<0>(a, acc);   // first quarter writes acc (no zero-init)
    rho_quarter<1>(a, acc);
    rho_quarter<2>(a, acc);
    rho_quarter<3>(a, acc);

    v2f sv = bc2(s);
#pragma unroll
    for (int jj = 0; jj < 4; ++jj)
#pragma unroll
      for (int i = 0; i < 8; ++i) a[jj][i] = acc[jj][i] * sv;
  }
  float rho = __expf(L);
  if (l == 0) Sign[(((b * 64 + n) * 64 + m) * 6 + 5) * 16 + k] = rho;
}

// ---------------- V body: V = einsum('bmd,dskv->bmskv') ----------------
__device__ __forceinline__ void v_body(int blk, const float* __restrict__ X,
                                       const float* __restrict__ Wv,
                                       float* __restrict__ V) {
  int t = blk * 256 + threadIdx.x;          // 196608 threads
  int bm = t / 1536; int rem = t - bm * 1536;
  int s = rem >> 8; int kk = (rem >> 4) & 15; int v = rem & 15;
  const float* x = X + bm * 16;
  float acc = 0.f;
#pragma unroll
  for (int d = 0; d < 16; ++d) acc += x[d] * Wv[((d * 6 + s) * 16 + kk) * 16 + v];
  V[t] = acc;
}

// ---------------- merged main: svd [0,2048) | rho [2048,4096) | V [4096,4864) ----------------
__global__ __launch_bounds__(256) void k_main(const float* __restrict__ Q,
                                              const float* __restrict__ K,
                                              const float* __restrict__ T,
                                              const float* __restrict__ detT,
                                              const float* __restrict__ X,
                                              const float* __restrict__ Wv,
                                              float* __restrict__ Sign,
                                              float* __restrict__ V) {
  int blk = blockIdx.x;
  if (blk < 2048)      svd_body(blk, Q, K, T, detT, Sign);
  else if (blk < 4096) rho_body(blk - 2048, Q, K, T, Sign);
  else                 v_body(blk - 4096, X, Wv, V);
}

// ---------------- out[b,n,v] = sum_{m,s,k} Sign * V ----------------
__global__ __launch_bounds__(256) void k_out(const float* __restrict__ Sign,
                                             const float* __restrict__ V,
                                             float* __restrict__ out) {
  __shared__ float red[256];
  int bn = blockIdx.x;              // 0..127
  int b = bn >> 6;
  int t = threadIdx.x;
  int v = t & 15, mc = t >> 4;      // m in [mc*4, mc*4+4)
  const float* sp = Sign + bn * 6144;
  const float* vp = V + b * 98304;
  float acc0 = 0.f, acc1 = 0.f;
  for (int mm = 0; mm < 4; ++mm) {
    int m = mc * 4 + mm;
    const v2f* sr = (const v2f*)(sp + m * 96);      // 96 floats, 16B-aligned
    const float* vr = vp + m * 1536 + v;
#pragma unroll
    for (int sk2 = 0; sk2 < 48; ++sk2) {
      v2f sv = sr[sk2];
      acc0 = fmaf(sv.x, vr[(2 * sk2) * 16], acc0);
      acc1 = fmaf(sv.y, vr[(2 * sk2 + 1) * 16], acc1);
    }
  }
  red[t] = acc0 + acc1;
  __syncthreads();
  for (int off = 128; off >= 16; off >>= 1) {
    if (t < off) red[t] += red[t + off];
    __syncthreads();
  }
  if (t < 16) out[bn * 16 + t] = red[t];
}

extern "C" void kernel_launch(void* const* d_in, const int* in_sizes, int n_in,
                              void* d_out, int out_size, void* d_ws, size_t ws_size,
                              hipStream_t stream) {
  const float* X  = (const float*)d_in[0];
  const float* Wk = (const float*)d_in[1];
  const float* Wq = (const float*)d_in[2];
  const float* T  = (const float*)d_in[3];
  const float* Wv = (const float*)d_in[4];
  float* out = (float*)d_out;
  float* ws = (float*)d_ws;

  float* Q    = ws + WS_Q;
  float* K    = ws + WS_K;
  float* detT = ws + WS_DETT;
  float* V    = ws + WS_V;
  float* Sign = ws + WS_SIGN;

  hipLaunchKernelGGL(k_setup, dim3(9),    dim3(256), 0, stream,
                     X, Wk, Wq, T, Q, K, detT);
  hipLaunchKernelGGL(k_main,  dim3(4864), dim3(256), 0, stream,
                     Q, K, T, detT, X, Wv, Sign, V);
  hipLaunchKernelGGL(k_out,   dim3(128),  dim3(256), 0, stream, Sign, V, out);
}